// Round 16
// baseline (103.456 us; speedup 1.0000x reference)
//
#include <hip/hip_runtime.h>
#include <hip/hip_fp16.h>

#define BB 4
#define NN 8192
#define DD 256
#define HH 8
#define MM 32768   // BB*NN

typedef __attribute__((ext_vector_type(8))) _Float16 half8;
typedef __attribute__((ext_vector_type(4))) _Float16 half4;
typedef __attribute__((ext_vector_type(4))) float f32x4;

#define GLL(src, dst)                                                        \
  __builtin_amdgcn_global_load_lds(                                          \
      (const __attribute__((address_space(1))) void*)(src),                  \
      (__attribute__((address_space(3))) void*)(dst), 16, 0, 0)

// ---------------- K0: W conversion ----------------
// W_qkv [256][1536] fp32 -> Wt [1536][256] fp16 (transposed)
__global__ void __launch_bounds__(256) k_cvt_w(const float* __restrict__ w,
                                               _Float16* __restrict__ wt) {
  int idx = blockIdx.x * 256 + threadIdx.x;  // 0..393215
  int k = idx / 1536, c = idx % 1536;
  wt[(size_t)c * 256 + k] = (_Float16)w[idx];
}

// ---------------- K1: kv GEMM + norm + rotary + fused dots-partial ----------------
// 64 rows, 8 heads, cols = k(64)+v(64). LDS shrunk to 50 KB -> 3 blocks/CU
// (12 waves) so cross-block waves hide the per-phase vmcnt(0) drain:
//   - 2-buffer W ring (16 KB each), classic 1-ahead prefetch, vmcnt(0)/phase
//   - dedicated kv scratch (stride 72, 18 KB); post-dots barrier DELETED
//     (kv reuse at head h+1 is ordered by the 4 intervening phase barriers)
__global__ void __launch_bounds__(256) k_qkv(const float* __restrict__ x,
                                             const _Float16* __restrict__ wt,
                                             const float* __restrict__ pos,
                                             _Float16* __restrict__ part16) {
  __shared__ alignas(16) _Float16 rbuf[2][8192];   // [128 cols][64 K] swizzled, 16 KB x2
  __shared__ alignas(16) _Float16 kvs[9216];       // kT [64 d][72]; vT at +4608, 18 KB
  const int row0 = blockIdx.x * 64;
  const int t = threadIdx.x;
  const int wv = t >> 6, l = t & 63, lr = l & 15, lg = l >> 4;
  const int myrow = row0 + wv * 16 + lr;

  // ---- x fragments: coalesced global loads, fp32 -> fp16, registers ----
  half8 afr[8];
#pragma unroll
  for (int c = 0; c < 8; ++c) {      // c = kt*2 + sp
    const float* src = x + (size_t)myrow * 256 + c * 32 + lg * 8;
    float4 a = *(const float4*)src;
    float4 b = *(const float4*)(src + 4);
    half8 hv;
    hv[0] = (_Float16)a.x; hv[1] = (_Float16)a.y; hv[2] = (_Float16)a.z; hv[3] = (_Float16)a.w;
    hv[4] = (_Float16)b.x; hv[5] = (_Float16)b.y; hv[6] = (_Float16)b.z; hv[7] = (_Float16)b.w;
    afr[c] = hv;
  }

  // ---- rotary angles (for k): freq index = lg*4+j ----
  const float px = pos[(size_t)myrow * 2 + 0] * 64.0f;
  const float py = pos[(size_t)myrow * 2 + 1] * 64.0f;
  float sxj[4], cxj[4], syj[4], cyj[4];
#pragma unroll
  for (int j = 0; j < 4; ++j) {
    float invf = exp2f((float)(lg * 4 + j) * -0.8304820237218405f);  // 10000^(-fi/16)
    __sincosf(px * invf, &sxj[j], &cxj[j]);
    __sincosf(py * invf, &syj[j], &cyj[j]);
  }

  // ---- W stage for phase p (p = h*4 + kt) -> rbuf[p&1]: k,v sections (128 cols) ----
  auto stageP = [&](int p) {
    const int hh = p >> 2, kt = p & 3;
    char* dst = (char*)&rbuf[p & 1][0];
#pragma unroll
    for (int call = 0; call < 4; ++call) {
      int ob = (call * 4 + wv) * 1024;             // wave-uniform dest base (bytes)
      int o = ob + l * 16;                         // this lane's dest byte
      int c = o >> 7;                              // col 0..127 (0-63=k, 64-127=v)
      int kb = (o & 127) ^ ((c & 7) << 4);         // logical K byte (XOR swizzle)
      int gc = ((c >> 6) + 1) * 512 + (hh << 6) + (c & 63);  // wt row (k/v sections)
      const char* src = (const char*)(wt + (size_t)gc * 256 + kt * 64) + kb;
      GLL(src, dst + ob);
    }
  };

  stageP(0);
  asm volatile("s_waitcnt vmcnt(0)" ::: "memory");   // buf0 ready
  __builtin_amdgcn_s_barrier();

#pragma unroll 1
  for (int h = 0; h < 8; ++h) {
    f32x4 acc[8] = {};                 // 0-3 = k, 4-7 = v
#pragma unroll
    for (int kt = 0; kt < 4; ++kt) {   // unrolled: afr static index
      const int p = h * 4 + kt;
      if (p < 31) stageP(p + 1);       // 1-ahead prefetch into rbuf[(p+1)&1]
      const char* wbp = (const char*)&rbuf[p & 1][0];
#pragma unroll
      for (int sp = 0; sp < 2; ++sp) {
        half8 af = afr[kt * 2 + sp];
        int wkb = sp * 64 + lg * 16;
#pragma unroll
        for (int cf = 0; cf < 8; ++cf) {
          int c = cf * 16 + lr;
          half8 bf = *(const half8*)(wbp + c * 128 + (wkb ^ ((c & 7) << 4)));
          // SWAPPED: A = W fragment, B = x fragment -> D[wcol][xrow]
          acc[cf] = __builtin_amdgcn_mfma_f32_16x16x32_f16(bf, af, acc[cf], 0, 0, 0);
        }
      }
      // drain stage(p+1); barrier also closes reads of rbuf[p&1] before
      // phase p+1 prefetches stage(p+2) into it
      asm volatile("s_waitcnt vmcnt(0)" ::: "memory");
      __builtin_amdgcn_s_barrier();
    }

    // ---- norms (in-wave): k = acc[0..3], v = acc[4..7] ----
    float sk = 0.f, sk2 = 0.f, sv = 0.f, sv2 = 0.f;
#pragma unroll
    for (int cc = 0; cc < 8; ++cc)
#pragma unroll
      for (int j = 0; j < 4; ++j) {
        float u = acc[cc][j];
        if (cc < 4) { sk += u; sk2 += u * u; } else { sv += u; sv2 += u * u; }
      }
    sk += __shfl_xor(sk, 16, 64);  sk += __shfl_xor(sk, 32, 64);
    sk2 += __shfl_xor(sk2, 16, 64); sk2 += __shfl_xor(sk2, 32, 64);
    sv += __shfl_xor(sv, 16, 64);  sv += __shfl_xor(sv, 32, 64);
    sv2 += __shfl_xor(sv2, 16, 64); sv2 += __shfl_xor(sv2, 32, 64);
    float mk = sk * 0.015625f, mv = sv * 0.015625f;
    float ik = rsqrtf(sk2 * 0.015625f - mk * mk + 1e-5f);
    float iv = rsqrtf(sv2 * 0.015625f - mv * mv + 1e-5f);

    half4 ok[4], ov[4];
#pragma unroll
    for (int j = 0; j < 4; ++j) {
      float k0 = (acc[0][j] - mk) * ik, k1 = (acc[1][j] - mk) * ik;
      float k2 = (acc[2][j] - mk) * ik, k3 = (acc[3][j] - mk) * ik;
      ok[0][j] = (_Float16)(k0 * cxj[j] - k1 * sxj[j]);
      ok[1][j] = (_Float16)(k1 * cxj[j] + k0 * sxj[j]);
      ok[2][j] = (_Float16)(k2 * cyj[j] - k3 * syj[j]);
      ok[3][j] = (_Float16)(k3 * cyj[j] + k2 * syj[j]);
      ov[0][j] = (_Float16)((acc[4][j] - mv) * iv);
      ov[1][j] = (_Float16)((acc[5][j] - mv) * iv);
      ov[2][j] = (_Float16)((acc[6][j] - mv) * iv);
      ov[3][j] = (_Float16)((acc[7][j] - mv) * iv);
    }
    // k,v -> kv scratch, transposed: kT[d][row], vT[e][row] (stride 72)
#pragma unroll
    for (int cc = 0; cc < 4; ++cc)
#pragma unroll
      for (int j = 0; j < 4; ++j) {
        int dr = (cc * 16 + lg * 4 + j) * 72 + wv * 16 + lr;
        kvs[dr] = ok[cc][j];
        kvs[4608 + dr] = ov[cc][j];
      }
    asm volatile("s_waitcnt lgkmcnt(0)" ::: "memory");   // kv writes visible
    __builtin_amdgcn_s_barrier();

    // ---- dots partial: D[d][e] = sum_rows kT[d][row] vT[e][row], K=64 ----
    f32x4 dacc[4] = {};
#pragma unroll
    for (int ks = 0; ks < 2; ++ks) {
      half8 adf = *(const half8*)(kvs + (wv * 16 + lr) * 72 + ks * 32 + lg * 8);
#pragma unroll
      for (int ep = 0; ep < 4; ++ep) {
        half8 bdf = *(const half8*)(kvs + 4608 + (ep * 16 + lr) * 72 + ks * 32 + lg * 8);
        dacc[ep] = __builtin_amdgcn_mfma_f32_16x16x32_f16(adf, bdf, dacc[ep], 0, 0, 0);
      }
    }
    // NO trailing barrier: head h+1's kv writes come after 4 phase barriers,
    // by which time these ds_reads (120-cyc latency) are long complete.

    // partial layout [e][d]: lane holds d = wv*16 + lg*4+{0..3}, e = ep*16+lr
    _Float16* pdst = part16 + ((size_t)blockIdx.x * 8 + h) * 4096;
#pragma unroll
    for (int ep = 0; ep < 4; ++ep) {
      half4 o;
#pragma unroll
      for (int j = 0; j < 4; ++j) o[j] = (_Float16)dacc[ep][j];
      *(half4*)(pdst + (ep * 16 + lr) * 64 + wv * 16 + lg * 4) = o;
    }
  }
}

// ---------------- K2: reduce 512 rowtile partials -> dots fp32 [32 bh][e*64+d] ----
__global__ void __launch_bounds__(256) k_pred(const _Float16* __restrict__ part16,
                                              float* __restrict__ dots) {
  __shared__ float red[4][512];
  const int bh = blockIdx.x >> 3, sl = blockIdx.x & 7;
  const int b = bh >> 3, h = bh & 7;
  const int t = threadIdx.x, wv = t >> 6, l = t & 63;
  float s[8] = {};
  const _Float16* base = part16 + ((size_t)(b * 128) * 8 + h) * 4096 + sl * 512 + l * 8;
#pragma unroll 4
  for (int i = 0; i < 32; ++i) {
    int rt = wv * 32 + i;
    half8 v = *(const half8*)(base + (size_t)rt * 32768);
#pragma unroll
    for (int m = 0; m < 8; ++m) s[m] += (float)v[m];
  }
#pragma unroll
  for (int m = 0; m < 8; ++m) red[wv][l * 8 + m] = s[m];
  __syncthreads();
#pragma unroll
  for (int e = t; e < 512; e += 256) {
    float r = red[0][e] + red[1][e] + red[2][e] + red[3][e];
    dots[(size_t)bh * 4096 + sl * 512 + e] = r;
  }
}

// ---------------- K2b: wdt[b][j][h*64+d] = (1/N) sum_e dotsT[e][d] wout[h*64+e][j]
// grid(32, 4): bid = b*8+h, j-quarter = blockIdx.y*64.
__global__ void __launch_bounds__(256) k_wd(const float* __restrict__ dots,
                                            const float* __restrict__ wout,
                                            _Float16* __restrict__ wdt) {
  __shared__ alignas(16) _Float16 a_lds[4096];    // [64 d][64 e] swizzled, 8 KB
  __shared__ alignas(16) _Float16 b_lds[4096];    // [64 jl][64 e] swizzled, 8 KB
  const int bid = blockIdx.x, b = bid >> 3, hh = bid & 7;
  const int j0 = blockIdx.y * 64;
  const int t = threadIdx.x, wv = t >> 6, l = t & 63, lr = l & 15, lg = l >> 4;

  // A: dots [e][d] fp32 -> a_lds [d][e] fp16 (scaled)
#pragma unroll
  for (int g = 0; g < 4; ++g) {
    int i4 = (g * 256 + t) * 4;  // 0..4095, e = i4>>6, d = i4&63
    f32x4 s = *(const f32x4*)(dots + (size_t)bid * 4096 + i4);
    int e = i4 >> 6, d0 = i4 & 63;
#pragma unroll
    for (int m = 0; m < 4; ++m) {
      int d = d0 + m;
      *(_Float16*)((char*)a_lds + d * 128 + ((e * 2) ^ ((d & 7) << 4))) =
          (_Float16)(s[m] * (1.0f / 8192.0f));
    }
  }
  // B: wout rows hh*64..+63, cols j0..+63, transposed to [jl][e] fp16
#pragma unroll
  for (int g = 0; g < 4; ++g) {
    int i4 = (g * 256 + t) * 4;  // 0..4095: e = i4>>6, jl = i4&63
    int e = i4 >> 6, jl0 = i4 & 63;
    f32x4 u = *(const f32x4*)(wout + (size_t)(hh * 64 + e) * 256 + j0 + jl0);
#pragma unroll
    for (int m = 0; m < 4; ++m) {
      int jl = jl0 + m;
      *(_Float16*)((char*)b_lds + jl * 128 + ((e * 2) ^ ((jl & 7) << 4))) = (_Float16)u[m];
    }
  }
  __syncthreads();

  f32x4 acc[4] = {};
#pragma unroll
  for (int sp = 0; sp < 2; ++sp) {
    int kb = sp * 64 + lg * 16;
    half8 bf;
    {
      int jl = wv * 16 + lr;
      bf = *(const half8*)((const char*)b_lds + jl * 128 + (kb ^ ((jl & 7) << 4)));
    }
#pragma unroll
    for (int ad = 0; ad < 4; ++ad) {
      int d = ad * 16 + lr;
      half8 af = *(const half8*)((const char*)a_lds + d * 128 + (kb ^ ((d & 7) << 4)));
      acc[ad] = __builtin_amdgcn_mfma_f32_16x16x32_f16(af, bf, acc[ad], 0, 0, 0);
    }
  }
  // D[row=d][col=j]: lane holds d = ad*16+lg*4+{0..3}, j = j0 + wv*16 + lr
#pragma unroll
  for (int ad = 0; ad < 4; ++ad) {
    int j = j0 + wv * 16 + lr;
    half4 o;
#pragma unroll
    for (int jj = 0; jj < 4; ++jj) o[jj] = (_Float16)acc[ad][jj];
    *(half4*)(wdt + (size_t)b * 131072 + (size_t)j * 512 + hh * 64 + ad * 16 + lg * 4) = o;
  }
}

// ---------------- K3: out = rope(x@Wq) @ wdt[b] + b_out  (q recomputed in-kernel) ----
// Per head h: 4 q-sub-phases (Wq 3-ring, 2 GLL/stage, swapped MFMA) -> rope ->
// q-tile to LDS (swizzled) -> out-MFMA (R13 map, B-reuse 2). wtile staged per head.
// Invariant: end-of-phase vmcnt(2) leaves only stage(p+2) -> stage(p+1) drained.
__global__ void __launch_bounds__(256) k_out(const float* __restrict__ x,
                                             const _Float16* __restrict__ wt,
                                             const float* __restrict__ pos,
                                             const _Float16* __restrict__ wdt,
                                             const float* __restrict__ bout,
                                             float* __restrict__ out) {
  __shared__ alignas(16) _Float16 wqr[3][4096];    // [64 qcols][64 K] swizzled, 8 KB x3
  __shared__ alignas(16) _Float16 qtile[4096];     // [64 rows][64 d] swizzled, 8 KB
  __shared__ alignas(16) _Float16 wtile[16384];    // [256 j][64 d] swizzled, 32 KB
  const int row0 = blockIdx.x * 64;
  const int b = row0 >> 13;
  const int t = threadIdx.x, wv = t >> 6, l = t & 63, lr = l & 15, lg = l >> 4;
  const int rh = wv >> 1, cq = wv & 1;
  const int myrow = row0 + wv * 16 + lr;

  // ---- x fragments in registers (same as k_qkv) ----
  half8 afr[8];
#pragma unroll
  for (int c = 0; c < 8; ++c) {
    const float* src = x + (size_t)myrow * 256 + c * 32 + lg * 8;
    float4 a = *(const float4*)src;
    float4 bb = *(const float4*)(src + 4);
    half8 hv;
    hv[0] = (_Float16)a.x; hv[1] = (_Float16)a.y; hv[2] = (_Float16)a.z; hv[3] = (_Float16)a.w;
    hv[4] = (_Float16)bb.x; hv[5] = (_Float16)bb.y; hv[6] = (_Float16)bb.z; hv[7] = (_Float16)bb.w;
    afr[c] = hv;
  }

  // ---- rotary angles (for q): freq index = lg*4+j ----
  const float px = pos[(size_t)myrow * 2 + 0] * 64.0f;
  const float py = pos[(size_t)myrow * 2 + 1] * 64.0f;
  float sxj[4], cxj[4], syj[4], cyj[4];
#pragma unroll
  for (int j = 0; j < 4; ++j) {
    float invf = exp2f((float)(lg * 4 + j) * -0.8304820237218405f);
    __sincosf(px * invf, &sxj[j], &cxj[j]);
    __sincosf(py * invf, &syj[j], &cyj[j]);
  }

  // ---- wtile stage for head hh: [256 j][64 d] from wdt[b][j][hh*64+d] (8 GLL) ----
  auto stageWT = [&](int hh) {
#pragma unroll
    for (int call = 0; call < 8; ++call) {
      int ob = (call * 4 + wv) * 1024;
      int o = ob + l * 16;
      int c = o >> 7;                              // j 0..255
      int kb = (o & 127) ^ ((c & 7) << 4);
      const char* src = (const char*)(wdt + (size_t)b * 131072 + (size_t)c * 512 + hh * 64) + kb;
      GLL(src, (char*)wtile + ob);
    }
  };
  // ---- Wq panel stage for phase p = h*4 + kt (2 GLL) ----
  auto stageWQ = [&](int p) {
    const int pd = p & 31;
    const int hq = pd >> 2, ktq = pd & 3;
    char* dst = (char*)&wqr[p % 3][0];
#pragma unroll
    for (int call = 0; call < 2; ++call) {
      int ob = (call * 4 + wv) * 1024;
      int o = ob + l * 16;
      int c = o >> 7;                              // q col 0..63
      int kb = (o & 127) ^ ((c & 7) << 4);
      int gc = (hq << 6) + (c & 63);               // wt row (q section = rows 0..511)
      const char* src = (const char*)(wt + (size_t)gc * 256 + ktq * 64) + kb;
      GLL(src, dst + ob);
    }
  };

  stageWT(0); stageWQ(0); stageWQ(1);
  asm volatile("s_waitcnt vmcnt(2)" ::: "memory");   // wtile(0)+wq(0) complete
  __builtin_amdgcn_s_barrier();

  f32x4 aco[8][2] = {};   // out accumulator, persists across heads
#pragma unroll 1
  for (int h = 0; h < 8; ++h) {
    // ---- q GEMM: 4 sub-phases, K=256 ----
    f32x4 aq[4] = {};
#pragma unroll
    for (int sub = 0; sub < 4; ++sub) {
      const int p = h * 4 + sub;
      stageWQ(p + 2);
      const char* wbp = (const char*)&wqr[p % 3][0];
#pragma unroll
      for (int sp = 0; sp < 2; ++sp) {
        half8 af = afr[sub * 2 + sp];
        int wkb = sp * 64 + lg * 16;
#pragma unroll
        for (int cf = 0; cf < 4; ++cf) {
          int c = cf * 16 + lr;
          half8 bf = *(const half8*)(wbp + c * 128 + (wkb ^ ((c & 7) << 4)));
          aq[cf] = __builtin_amdgcn_mfma_f32_16x16x32_f16(bf, af, aq[cf], 0, 0, 0);
        }
      }
      // counted: leave only stage(p+2) [2 ops] -> stage(p+1) + wtile drained
      asm volatile("s_waitcnt vmcnt(2)" ::: "memory");
      __builtin_amdgcn_s_barrier();
    }
    // ---- rope + q-tile write (lane holds q-cols cf*16+lg*4+j of row lr) ----
    {
      half4 oq[4];
#pragma unroll
      for (int j = 0; j < 4; ++j) {
        float q0 = aq[0][j], q1 = aq[1][j], q2 = aq[2][j], q3 = aq[3][j];
        oq[0][j] = (_Float16)(q0 * cxj[j] - q1 * sxj[j]);
        oq[1][j] = (_Float16)(q1 * cxj[j] + q0 * sxj[j]);
        oq[2][j] = (_Float16)(q2 * cyj[j] - q3 * syj[j]);
        oq[3][j] = (_Float16)(q3 * cyj[j] + q2 * syj[j]);
      }
      int row = wv * 16 + lr;
#pragma unroll
      for (int cc = 0; cc < 4; ++cc)
        *(half4*)((char*)qtile + row * 128 + ((cc * 32 + lg * 8) ^ ((row & 7) << 4))) = oq[cc];
    }
    asm volatile("s_waitcnt lgkmcnt(0)" ::: "memory");
    __builtin_amdgcn_s_barrier();

    // ---- out-MFMA: K=64 (head h). waves (rh,cq), B-reuse 2 (R13-verified map) ----
#pragma unroll
    for (int sp = 0; sp < 2; ++sp) {
      int kb = sp * 64 + lg * 16;
      half8 af2[2];
#pragma unroll
      for (int rs = 0; rs < 2; ++rs) {
        int arow = rh * 32 + rs * 16 + lr;
        af2[rs] = *(const half8*)((const char*)qtile + arow * 128 + (kb ^ ((arow & 7) << 4)));
      }
#pragma unroll
      for (int cf = 0; cf < 8; ++cf) {
        int c = cq * 128 + cf * 16 + lr;
        half8 bf = *(const half8*)((const char*)wtile + c * 128 + (kb ^ ((c & 7) << 4)));
#pragma unroll
        for (int rs = 0; rs < 2; ++rs)
          aco[cf][rs] = __builtin_amdgcn_mfma_f32_16x16x32_f16(af2[rs], bf, aco[cf][rs], 0, 0, 0);
      }
    }
    asm volatile("s_waitcnt lgkmcnt(0)" ::: "memory");   // qtile/wtile reads done
    __builtin_amdgcn_s_barrier();
    if (h < 7) stageWT(h + 1);                           // restage after reads complete
  }
  // ---- store (R13 exact) ----
#pragma unroll
  for (int cf = 0; cf < 8; ++cf) {
    int col = cq * 128 + cf * 16 + lr;
    float bo = bout[col];
#pragma unroll
    for (int rs = 0; rs < 2; ++rs)
#pragma unroll
      for (int j = 0; j < 4; ++j) {
        int grow = row0 + rh * 32 + rs * 16 + lg * 4 + j;
        out[(size_t)grow * 256 + col] = aco[cf][rs][j] + bo;
      }
  }
}

// ---------------- launch ----------------
extern "C" void kernel_launch(void* const* d_in, const int* in_sizes, int n_in,
                              void* d_out, int out_size, void* d_ws, size_t ws_size,
                              hipStream_t stream) {
  const float* x    = (const float*)d_in[0];
  const float* pos  = (const float*)d_in[1];
  const float* wqkv = (const float*)d_in[2];
  const float* wout = (const float*)d_in[3];
  const float* bout = (const float*)d_in[4];
  float* out = (float*)d_out;
  char* ws = (char*)d_ws;

  _Float16* wt16   = (_Float16*)(ws + 0);          //    786,432 B
  _Float16* part16 = (_Float16*)(ws + 786432);     // 33,554,432 B
  float*    dots   = (float*)   (ws + 34340864);   //    524,288 B
  _Float16* wdt    = (_Float16*)(ws + 34865152);   //  1,048,576 B (end 35,913,728)

  k_cvt_w<<<1536, 256, 0, stream>>>(wqkv, wt16);
  k_qkv<<<512, 256, 0, stream>>>(x, wt16, pos, part16);
  k_pred<<<256, 256, 0, stream>>>(part16, dots);
  k_wd<<<dim3(32, 4), 256, 0, stream>>>(dots, wout, wdt);
  k_out<<<512, 256, 0, stream>>>(x, wt16, pos, wdt, bout, out);
}

// Round 17
// 103.315 us; speedup vs baseline: 1.0014x; 1.0014x over previous
//
#include <hip/hip_runtime.h>
#include <hip/hip_fp16.h>

#define BB 4
#define NN 8192
#define DD 256
#define HH 8
#define MM 32768   // BB*NN

typedef __attribute__((ext_vector_type(8))) _Float16 half8;
typedef __attribute__((ext_vector_type(4))) _Float16 half4;
typedef __attribute__((ext_vector_type(4))) float f32x4;

#define GLL(src, dst)                                                        \
  __builtin_amdgcn_global_load_lds(                                          \
      (const __attribute__((address_space(1))) void*)(src),                  \
      (__attribute__((address_space(3))) void*)(dst), 16, 0, 0)

// ---------------- K0: W conversion ----------------
// W_qkv [256][1536] fp32 -> Wt [1536][256] fp16 (transposed)
__global__ void __launch_bounds__(256) k_cvt_w(const float* __restrict__ w,
                                               _Float16* __restrict__ wt) {
  int idx = blockIdx.x * 256 + threadIdx.x;  // 0..393215
  int k = idx / 1536, c = idx % 1536;
  wt[(size_t)c * 256 + k] = (_Float16)w[idx];
}

// ---------------- K1: kv GEMM + norm + rotary + fused dots-partial ----------------
// [R15-exact, best verified: ~48 us] 64 rows, 8 heads, cols = k(64)+v(64).
// 3-buffer W ring (4 GLL/stage), counted vmcnt(4): stage(p+1) drained at end
// of phase p, stage(p+2) stays in flight. kv scratch = dead ring buffer.
__global__ void __launch_bounds__(256) k_qkv(const float* __restrict__ x,
                                             const _Float16* __restrict__ wt,
                                             const float* __restrict__ pos,
                                             _Float16* __restrict__ part16) {
  __shared__ alignas(16) _Float16 rbuf[3][12288];
  const int row0 = blockIdx.x * 64;
  const int t = threadIdx.x;
  const int wv = t >> 6, l = t & 63, lr = l & 15, lg = l >> 4;
  const int myrow = row0 + wv * 16 + lr;

  half8 afr[8];
#pragma unroll
  for (int c = 0; c < 8; ++c) {      // c = kt*2 + sp
    const float* src = x + (size_t)myrow * 256 + c * 32 + lg * 8;
    float4 a = *(const float4*)src;
    float4 b = *(const float4*)(src + 4);
    half8 hv;
    hv[0] = (_Float16)a.x; hv[1] = (_Float16)a.y; hv[2] = (_Float16)a.z; hv[3] = (_Float16)a.w;
    hv[4] = (_Float16)b.x; hv[5] = (_Float16)b.y; hv[6] = (_Float16)b.z; hv[7] = (_Float16)b.w;
    afr[c] = hv;
  }

  const float px = pos[(size_t)myrow * 2 + 0] * 64.0f;
  const float py = pos[(size_t)myrow * 2 + 1] * 64.0f;
  float sxj[4], cxj[4], syj[4], cyj[4];
#pragma unroll
  for (int j = 0; j < 4; ++j) {
    float invf = exp2f((float)(lg * 4 + j) * -0.8304820237218405f);  // 10000^(-fi/16)
    __sincosf(px * invf, &sxj[j], &cxj[j]);
    __sincosf(py * invf, &syj[j], &cyj[j]);
  }

  auto stageP = [&](int p) {
    const int pd = p & 31;
    const int hh = pd >> 2, kt = pd & 3;
    char* dst = (char*)&rbuf[p % 3][0];
#pragma unroll
    for (int call = 0; call < 4; ++call) {
      int ob = (call * 4 + wv) * 1024;
      int o = ob + l * 16;
      int c = o >> 7;                              // col 0..127 (0-63=k, 64-127=v)
      int kb = (o & 127) ^ ((c & 7) << 4);
      int gc = ((c >> 6) + 1) * 512 + (hh << 6) + (c & 63);
      const char* src = (const char*)(wt + (size_t)gc * 256 + kt * 64) + kb;
      GLL(src, dst + ob);
    }
  };

  stageP(0); stageP(1);
  asm volatile("s_waitcnt vmcnt(4)" ::: "memory");   // stage(0) complete
  __builtin_amdgcn_s_barrier();

#pragma unroll 1
  for (int h = 0; h < 8; ++h) {
    f32x4 acc[8] = {};                 // 0-3 = k, 4-7 = v
#pragma unroll
    for (int kt = 0; kt < 4; ++kt) {
      const int p = h * 4 + kt;
      stageP(p + 2);
      const char* wbp = (const char*)&rbuf[p % 3][0];
#pragma unroll
      for (int sp = 0; sp < 2; ++sp) {
        half8 af = afr[kt * 2 + sp];
        int wkb = sp * 64 + lg * 16;
#pragma unroll
        for (int cf = 0; cf < 8; ++cf) {
          int c = cf * 16 + lr;
          half8 bf = *(const half8*)(wbp + c * 128 + (wkb ^ ((c & 7) << 4)));
          acc[cf] = __builtin_amdgcn_mfma_f32_16x16x32_f16(bf, af, acc[cf], 0, 0, 0);
        }
      }
      asm volatile("s_waitcnt vmcnt(4)" ::: "memory");
      __builtin_amdgcn_s_barrier();
    }
    _Float16* dead = &rbuf[h % 3][0];   // kT: [64 d][88 rows]; vT at +5632 halfs

    float sk = 0.f, sk2 = 0.f, sv = 0.f, sv2 = 0.f;
#pragma unroll
    for (int cc = 0; cc < 8; ++cc)
#pragma unroll
      for (int j = 0; j < 4; ++j) {
        float u = acc[cc][j];
        if (cc < 4) { sk += u; sk2 += u * u; } else { sv += u; sv2 += u * u; }
      }
    sk += __shfl_xor(sk, 16, 64);  sk += __shfl_xor(sk, 32, 64);
    sk2 += __shfl_xor(sk2, 16, 64); sk2 += __shfl_xor(sk2, 32, 64);
    sv += __shfl_xor(sv, 16, 64);  sv += __shfl_xor(sv, 32, 64);
    sv2 += __shfl_xor(sv2, 16, 64); sv2 += __shfl_xor(sv2, 32, 64);
    float mk = sk * 0.015625f, mv = sv * 0.015625f;
    float ik = rsqrtf(sk2 * 0.015625f - mk * mk + 1e-5f);
    float iv = rsqrtf(sv2 * 0.015625f - mv * mv + 1e-5f);

    half4 ok[4], ov[4];
#pragma unroll
    for (int j = 0; j < 4; ++j) {
      float k0 = (acc[0][j] - mk) * ik, k1 = (acc[1][j] - mk) * ik;
      float k2 = (acc[2][j] - mk) * ik, k3 = (acc[3][j] - mk) * ik;
      ok[0][j] = (_Float16)(k0 * cxj[j] - k1 * sxj[j]);
      ok[1][j] = (_Float16)(k1 * cxj[j] + k0 * sxj[j]);
      ok[2][j] = (_Float16)(k2 * cyj[j] - k3 * syj[j]);
      ok[3][j] = (_Float16)(k3 * cyj[j] + k2 * syj[j]);
      ov[0][j] = (_Float16)((acc[4][j] - mv) * iv);
      ov[1][j] = (_Float16)((acc[5][j] - mv) * iv);
      ov[2][j] = (_Float16)((acc[6][j] - mv) * iv);
      ov[3][j] = (_Float16)((acc[7][j] - mv) * iv);
    }
#pragma unroll
    for (int cc = 0; cc < 4; ++cc)
#pragma unroll
      for (int j = 0; j < 4; ++j) {
        int dr = (cc * 16 + lg * 4 + j) * 88 + wv * 16 + lr;
        dead[dr] = ok[cc][j];
        dead[5632 + dr] = ov[cc][j];
      }
    asm volatile("s_waitcnt lgkmcnt(0)" ::: "memory");
    __builtin_amdgcn_s_barrier();

    f32x4 dacc[4] = {};
#pragma unroll
    for (int ks = 0; ks < 2; ++ks) {
      half8 adf = *(const half8*)(dead + (wv * 16 + lr) * 88 + ks * 32 + lg * 8);
#pragma unroll
      for (int ep = 0; ep < 4; ++ep) {
        half8 bdf = *(const half8*)(dead + 5632 + (ep * 16 + lr) * 88 + ks * 32 + lg * 8);
        dacc[ep] = __builtin_amdgcn_mfma_f32_16x16x32_f16(adf, bdf, dacc[ep], 0, 0, 0);
      }
    }
    asm volatile("s_waitcnt lgkmcnt(0)" ::: "memory");
    __builtin_amdgcn_s_barrier();

    _Float16* pdst = part16 + ((size_t)blockIdx.x * 8 + h) * 4096;
#pragma unroll
    for (int ep = 0; ep < 4; ++ep) {
      half4 o;
#pragma unroll
      for (int j = 0; j < 4; ++j) o[j] = (_Float16)dacc[ep][j];
      *(half4*)(pdst + (ep * 16 + lr) * 64 + wv * 16 + lg * 4) = o;
    }
  }
}

// ---------------- K2: reduce 512 rowtile partials -> dots fp32 [32 bh][e*64+d] ----
__global__ void __launch_bounds__(256) k_pred(const _Float16* __restrict__ part16,
                                              float* __restrict__ dots) {
  __shared__ float red[4][512];
  const int bh = blockIdx.x >> 3, sl = blockIdx.x & 7;
  const int b = bh >> 3, h = bh & 7;
  const int t = threadIdx.x, wv = t >> 6, l = t & 63;
  float s[8] = {};
  const _Float16* base = part16 + ((size_t)(b * 128) * 8 + h) * 4096 + sl * 512 + l * 8;
#pragma unroll 4
  for (int i = 0; i < 32; ++i) {
    int rt = wv * 32 + i;
    half8 v = *(const half8*)(base + (size_t)rt * 32768);
#pragma unroll
    for (int m = 0; m < 8; ++m) s[m] += (float)v[m];
  }
#pragma unroll
  for (int m = 0; m < 8; ++m) red[wv][l * 8 + m] = s[m];
  __syncthreads();
#pragma unroll
  for (int e = t; e < 512; e += 256) {
    float r = red[0][e] + red[1][e] + red[2][e] + red[3][e];
    dots[(size_t)bh * 4096 + sl * 512 + e] = r;
  }
}

// ---------------- K2b: wdt[b][j][h*64+d] = (1/N) sum_e dotsT[e][d] wout[h*64+e][j]
__global__ void __launch_bounds__(256) k_wd(const float* __restrict__ dots,
                                            const float* __restrict__ wout,
                                            _Float16* __restrict__ wdt) {
  __shared__ alignas(16) _Float16 a_lds[4096];
  __shared__ alignas(16) _Float16 b_lds[4096];
  const int bid = blockIdx.x, b = bid >> 3, hh = bid & 7;
  const int j0 = blockIdx.y * 64;
  const int t = threadIdx.x, wv = t >> 6, l = t & 63, lr = l & 15, lg = l >> 4;

#pragma unroll
  for (int g = 0; g < 4; ++g) {
    int i4 = (g * 256 + t) * 4;
    f32x4 s = *(const f32x4*)(dots + (size_t)bid * 4096 + i4);
    int e = i4 >> 6, d0 = i4 & 63;
#pragma unroll
    for (int m = 0; m < 4; ++m) {
      int d = d0 + m;
      *(_Float16*)((char*)a_lds + d * 128 + ((e * 2) ^ ((d & 7) << 4))) =
          (_Float16)(s[m] * (1.0f / 8192.0f));
    }
  }
#pragma unroll
  for (int g = 0; g < 4; ++g) {
    int i4 = (g * 256 + t) * 4;
    int e = i4 >> 6, jl0 = i4 & 63;
    f32x4 u = *(const f32x4*)(wout + (size_t)(hh * 64 + e) * 256 + j0 + jl0);
#pragma unroll
    for (int m = 0; m < 4; ++m) {
      int jl = jl0 + m;
      *(_Float16*)((char*)b_lds + jl * 128 + ((e * 2) ^ ((jl & 7) << 4))) = (_Float16)u[m];
    }
  }
  __syncthreads();

  f32x4 acc[4] = {};
#pragma unroll
  for (int sp = 0; sp < 2; ++sp) {
    int kb = sp * 64 + lg * 16;
    half8 bf;
    {
      int jl = wv * 16 + lr;
      bf = *(const half8*)((const char*)b_lds + jl * 128 + (kb ^ ((jl & 7) << 4)));
    }
#pragma unroll
    for (int ad = 0; ad < 4; ++ad) {
      int d = ad * 16 + lr;
      half8 af = *(const half8*)((const char*)a_lds + d * 128 + (kb ^ ((d & 7) << 4)));
      acc[ad] = __builtin_amdgcn_mfma_f32_16x16x32_f16(af, bf, acc[ad], 0, 0, 0);
    }
  }
#pragma unroll
  for (int ad = 0; ad < 4; ++ad) {
    int j = j0 + wv * 16 + lr;
    half4 o;
#pragma unroll
    for (int jj = 0; jj < 4; ++jj) o[jj] = (_Float16)acc[ad][jj];
    *(half4*)(wdt + (size_t)b * 131072 + (size_t)j * 512 + hh * 64 + ad * 16 + lg * 4) = o;
  }
}

// ---------------- K3: out = rope(x@Wq) @ wdt[b] + b_out ----------------
// v2: whole-head Wq buffer (4 panels, 32 KB) -> q-GEMM with NO internal barriers,
// B-reuse 2 via waves (rh, qh). 3 barriers/head (was 6). Stage overlap:
// wq(h+1) issues during out-MFMA; wtile(h+1) after post-out barrier;
// head-start vmcnt(8) leaves wtile(h+1) in flight.
__global__ void __launch_bounds__(256) k_out(const float* __restrict__ x,
                                             const _Float16* __restrict__ wt,
                                             const float* __restrict__ pos,
                                             const _Float16* __restrict__ wdt,
                                             const float* __restrict__ bout,
                                             float* __restrict__ out) {
  __shared__ alignas(16) _Float16 wqs[16384];      // 4 panels x [64 c][64 K], 32 KB
  __shared__ alignas(16) _Float16 qtile[4096];     // [64 rows][64 d] swizzled, 8 KB
  __shared__ alignas(16) _Float16 wtile[16384];    // [256 j][64 d] swizzled, 32 KB
  const int row0 = blockIdx.x * 64;
  const int b = row0 >> 13;
  const int t = threadIdx.x, wv = t >> 6, l = t & 63, lr = l & 15, lg = l >> 4;
  const int rh = wv >> 1, qh = wv & 1;             // q-GEMM: row-half, q-col-half
  const int cq = wv & 1;                           // out-MFMA: j-col half (same wv bit)

  // ---- x fragments for BOTH row-frags (rows rh*32 + rs*16 + lr) ----
  half8 afr[2][8];
#pragma unroll
  for (int rs = 0; rs < 2; ++rs)
#pragma unroll
    for (int c = 0; c < 8; ++c) {
      const float* src = x + (size_t)(row0 + rh * 32 + rs * 16 + lr) * 256 + c * 32 + lg * 8;
      float4 a = *(const float4*)src;
      float4 bb = *(const float4*)(src + 4);
      half8 hv;
      hv[0] = (_Float16)a.x; hv[1] = (_Float16)a.y; hv[2] = (_Float16)a.z; hv[3] = (_Float16)a.w;
      hv[4] = (_Float16)bb.x; hv[5] = (_Float16)bb.y; hv[6] = (_Float16)bb.z; hv[7] = (_Float16)bb.w;
      afr[rs][c] = hv;
    }

  // ---- rotary angles for this wave's dim (qh=0: x, qh=1: y), per row-frag ----
  float sa[2][4], ca[2][4];
#pragma unroll
  for (int rs = 0; rs < 2; ++rs) {
    float p = pos[(size_t)(row0 + rh * 32 + rs * 16 + lr) * 2 + qh] * 64.0f;
#pragma unroll
    for (int j = 0; j < 4; ++j) {
      float invf = exp2f((float)(lg * 4 + j) * -0.8304820237218405f);
      __sincosf(p * invf, &sa[rs][j], &ca[rs][j]);
    }
  }

  // ---- wtile stage for head hh: [256 j][64 d] (8 GLL) ----
  auto stageWT = [&](int hh) {
#pragma unroll
    for (int call = 0; call < 8; ++call) {
      int ob = (call * 4 + wv) * 1024;
      int o = ob + l * 16;
      int c = o >> 7;                              // j 0..255
      int kb = (o & 127) ^ ((c & 7) << 4);
      const char* src = (const char*)(wdt + (size_t)b * 131072 + (size_t)c * 512 + hh * 64) + kb;
      GLL(src, (char*)wtile + ob);
    }
  };
  // ---- Wq stage for head hh: 4 panels (kt=0..3), 8 GLL total ----
  auto stageWQ = [&](int hh) {
#pragma unroll
    for (int c2 = 0; c2 < 8; ++c2) {
      int panel = c2 >> 1, wc = c2 & 1;
      int obp = (wc * 4 + wv) * 1024;              // within-panel byte
      int o = obp + l * 16;
      int c = o >> 7;                              // q col 0..63
      int kb = (o & 127) ^ ((c & 7) << 4);
      int gc = (hh << 6) + c;                      // wt row (q section)
      const char* src = (const char*)(wt + (size_t)gc * 256 + panel * 64) + kb;
      GLL(src, (char*)wqs + panel * 8192 + obp);
    }
  };

  stageWQ(0); stageWT(0);
  asm volatile("s_waitcnt vmcnt(8)" ::: "memory");   // wq(0) complete, wtile(0) in flight
  __builtin_amdgcn_s_barrier();

  f32x4 aco[8][2] = {};   // out accumulator, persists across heads
#pragma unroll 1
  for (int h = 0; h < 8; ++h) {
    // ---- A: q-GEMM, K=256, no internal barriers (all 4 panels resident) ----
    f32x4 aq[2][2] = {};   // [cf][rs]
#pragma unroll
    for (int sub = 0; sub < 4; ++sub)
#pragma unroll
      for (int sp = 0; sp < 2; ++sp) {
        int wkb = sp * 64 + lg * 16;
#pragma unroll
        for (int cf = 0; cf < 2; ++cf) {
          int c = qh * 32 + cf * 16 + lr;
          half8 bf = *(const half8*)((const char*)wqs + sub * 8192 + c * 128 +
                                     (wkb ^ ((c & 7) << 4)));
#pragma unroll
          for (int rs = 0; rs < 2; ++rs)
            aq[cf][rs] = __builtin_amdgcn_mfma_f32_16x16x32_f16(
                bf, afr[rs][sub * 2 + sp], aq[cf][rs], 0, 0, 0);
        }
      }
    // ---- B: rope + qtile write. lane holds cols qh*32+cf*16+lg*4+j of rows rh*32+rs*16+lr
#pragma unroll
    for (int rs = 0; rs < 2; ++rs) {
      half4 o0, o1;
#pragma unroll
      for (int j = 0; j < 4; ++j) {
        float a0 = aq[0][rs][j], a1 = aq[1][rs][j];
        o0[j] = (_Float16)(a0 * ca[rs][j] - a1 * sa[rs][j]);
        o1[j] = (_Float16)(a1 * ca[rs][j] + a0 * sa[rs][j]);
      }
      int r = rh * 32 + rs * 16 + lr;
      int cb0 = (qh * 32 + lg * 4) * 2;            // byte col of o0
      *(half4*)((char*)qtile + r * 128 + (cb0 ^ ((r & 7) << 4))) = o0;
      *(half4*)((char*)qtile + r * 128 + ((cb0 + 32) ^ ((r & 7) << 4))) = o1;
    }
    // ---- C: wtile(h) arrived + qtile visible ----
    asm volatile("s_waitcnt vmcnt(0) lgkmcnt(0)" ::: "memory");
    __builtin_amdgcn_s_barrier();
    // ---- D: wq(h+1) into wqs (dead: all q-GEMM reads closed by C) ----
    if (h < 7) stageWQ(h + 1);

    // ---- E: out-MFMA, K=64. waves (rh, cq), B-reuse 2 (R13-verified map) ----
#pragma unroll
    for (int sp = 0; sp < 2; ++sp) {
      int kb = sp * 64 + lg * 16;
      half8 af2[2];
#pragma unroll
      for (int rs = 0; rs < 2; ++rs) {
        int arow = rh * 32 + rs * 16 + lr;
        af2[rs] = *(const half8*)((const char*)qtile + arow * 128 + (kb ^ ((arow & 7) << 4)));
      }
#pragma unroll
      for (int cf = 0; cf < 8; ++cf) {
        int c = cq * 128 + cf * 16 + lr;
        half8 bf = *(const half8*)((const char*)wtile + c * 128 + (kb ^ ((c & 7) << 4)));
#pragma unroll
        for (int rs = 0; rs < 2; ++rs)
          aco[cf][rs] = __builtin_amdgcn_mfma_f32_16x16x32_f16(af2[rs], bf, aco[cf][rs], 0, 0, 0);
      }
    }
    // ---- F: qtile/wtile reads closed ----
    asm volatile("s_waitcnt lgkmcnt(0)" ::: "memory");
    __builtin_amdgcn_s_barrier();
    // ---- G: wtile(h+1); H: wq(h+1) ready (vmcnt(8) leaves wtile in flight) ----
    if (h < 7) {
      stageWT(h + 1);
      asm volatile("s_waitcnt vmcnt(8)" ::: "memory");
      __builtin_amdgcn_s_barrier();
    }
  }
  // ---- store (R13 exact) ----
#pragma unroll
  for (int cf = 0; cf < 8; ++cf) {
    int col = cq * 128 + cf * 16 + lr;
    float bo = bout[col];
#pragma unroll
    for (int rs = 0; rs < 2; ++rs)
#pragma unroll
      for (int j = 0; j < 4; ++j) {
        int grow = row0 + rh * 32 + rs * 16 + lg * 4 + j;
        out[(size_t)grow * 256 + col] = aco[cf][rs][j] + bo;
      }
  }
}

// ---------------- launch ----------------
extern "C" void kernel_launch(void* const* d_in, const int* in_sizes, int n_in,
                              void* d_out, int out_size, void* d_ws, size_t ws_size,
                              hipStream_t stream) {
  const float* x    = (const float*)d_in[0];
  const float* pos  = (const float*)d_in[1];
  const float* wqkv = (const float*)d_in[2];
  const float* wout = (const float*)d_in[3];
  const float* bout = (const float*)d_in[4];
  float* out = (float*)d_out;
  char* ws = (char*)d_ws;

  _Float16* wt16   = (_Float16*)(ws + 0);          //    786,432 B
  _Float16* part16 = (_Float16*)(ws + 786432);     // 33,554,432 B
  float*    dots   = (float*)   (ws + 34340864);   //    524,288 B
  _Float16* wdt    = (_Float16*)(ws + 34865152);   //  1,048,576 B (end 35,913,728)

  k_cvt_w<<<1536, 256, 0, stream>>>(wqkv, wt16);
  k_qkv<<<512, 256, 0, stream>>>(x, wt16, pos, part16);
  k_pred<<<256, 256, 0, stream>>>(part16, dots);
  k_wd<<<dim3(32, 4), 256, 0, stream>>>(dots, wout, wdt);
  k_out<<<512, 256, 0, stream>>>(x, wt16, pos, wdt, bout, out);
}

// Round 19
// 102.185 us; speedup vs baseline: 1.0124x; 1.0111x over previous
//
#include <hip/hip_runtime.h>
#include <hip/hip_fp16.h>

#define BB 4
#define NN 8192
#define DD 256
#define HH 8
#define MM 32768   // BB*NN

typedef __attribute__((ext_vector_type(8))) _Float16 half8;
typedef __attribute__((ext_vector_type(4))) _Float16 half4;
typedef __attribute__((ext_vector_type(4))) float f32x4;

#define GLL(src, dst)                                                        \
  __builtin_amdgcn_global_load_lds(                                          \
      (const __attribute__((address_space(1))) void*)(src),                  \
      (__attribute__((address_space(3))) void*)(dst), 16, 0, 0)

// ---------------- K0: W conversion ----------------
// W_qkv [256][1536] fp32 -> Wt [1536][256] fp16 (transposed)
__global__ void __launch_bounds__(256) k_cvt_w(const float* __restrict__ w,
                                               _Float16* __restrict__ wt) {
  int idx = blockIdx.x * 256 + threadIdx.x;  // 0..393215
  int k = idx / 1536, c = idx % 1536;
  wt[(size_t)c * 256 + k] = (_Float16)w[idx];
}

// ---------------- K1: kv GEMM + norm + rotary + fused dots-partial ----------------
// grid(1024): rowtile = bid>>1 (64 rows), h0 = (bid&1)*4 (4 heads, 16 phases).
// Ring slots 16 KB; kv scratch = XOR-swizzled [64 d][64 r] inside the dead slot
// -> LDS 48 KB -> 3 blocks/CU. UNIFORM staging (pd = p & 15, unconditional):
// every phase issues 4 ops so vmcnt(4) always drains stage(p+1). Tail stages
// (16,17) land in rbuf[1]/rbuf[2], never touching the h=3 dead slot rbuf[0].
__global__ void __launch_bounds__(256) k_qkv(const float* __restrict__ x,
                                             const _Float16* __restrict__ wt,
                                             const float* __restrict__ pos,
                                             _Float16* __restrict__ part16) {
  __shared__ alignas(16) _Float16 rbuf[3][8192];   // 16 KB x3
  const int bid = blockIdx.x;
  const int rowtile = bid >> 1;
  const int row0 = rowtile * 64;
  const int h0 = (bid & 1) * 4;
  const int t = threadIdx.x;
  const int wv = t >> 6, l = t & 63, lr = l & 15, lg = l >> 4;
  const int myrow = row0 + wv * 16 + lr;

  half8 afr[8];
#pragma unroll
  for (int c = 0; c < 8; ++c) {      // c = kt*2 + sp
    const float* src = x + (size_t)myrow * 256 + c * 32 + lg * 8;
    float4 a = *(const float4*)src;
    float4 b = *(const float4*)(src + 4);
    half8 hv;
    hv[0] = (_Float16)a.x; hv[1] = (_Float16)a.y; hv[2] = (_Float16)a.z; hv[3] = (_Float16)a.w;
    hv[4] = (_Float16)b.x; hv[5] = (_Float16)b.y; hv[6] = (_Float16)b.z; hv[7] = (_Float16)b.w;
    afr[c] = hv;
  }

  const float px = pos[(size_t)myrow * 2 + 0] * 64.0f;
  const float py = pos[(size_t)myrow * 2 + 1] * 64.0f;
  float sxj[4], cxj[4], syj[4], cyj[4];
#pragma unroll
  for (int j = 0; j < 4; ++j) {
    float invf = exp2f((float)(lg * 4 + j) * -0.8304820237218405f);  // 10000^(-fi/16)
    __sincosf(px * invf, &sxj[j], &cxj[j]);
    __sincosf(py * invf, &syj[j], &cyj[j]);
  }

  // ---- W stage for phase p (data index wraps mod 16): k,v sections ----
  auto stageP = [&](int p) {
    const int pd = p & 15;
    const int hh = h0 + (pd >> 2), kt = pd & 3;
    char* dst = (char*)&rbuf[p % 3][0];
#pragma unroll
    for (int call = 0; call < 4; ++call) {
      int ob = (call * 4 + wv) * 1024;
      int o = ob + l * 16;
      int c = o >> 7;                              // col 0..127 (0-63=k, 64-127=v)
      int kb = (o & 127) ^ ((c & 7) << 4);
      int gc = ((c >> 6) + 1) * 512 + (hh << 6) + (c & 63);
      const char* src = (const char*)(wt + (size_t)gc * 256 + kt * 64) + kb;
      GLL(src, dst + ob);
    }
  };

  stageP(0); stageP(1);
  asm volatile("s_waitcnt vmcnt(4)" ::: "memory");   // stage(0) complete
  __builtin_amdgcn_s_barrier();

#pragma unroll 1
  for (int h = 0; h < 4; ++h) {
    const int habs = h0 + h;
    f32x4 acc[8] = {};                 // 0-3 = k, 4-7 = v
#pragma unroll
    for (int kt = 0; kt < 4; ++kt) {
      const int p = h * 4 + kt;
      stageP(p + 2);                   // UNCONDITIONAL: uniform op-count
      const char* wbp = (const char*)&rbuf[p % 3][0];
#pragma unroll
      for (int sp = 0; sp < 2; ++sp) {
        half8 af = afr[kt * 2 + sp];
        int wkb = sp * 64 + lg * 16;
#pragma unroll
        for (int cf = 0; cf < 8; ++cf) {
          int c = cf * 16 + lr;
          half8 bf = *(const half8*)(wbp + c * 128 + (wkb ^ ((c & 7) << 4)));
          // SWAPPED: A = W fragment, B = x fragment -> D[wcol][xrow]
          acc[cf] = __builtin_amdgcn_mfma_f32_16x16x32_f16(bf, af, acc[cf], 0, 0, 0);
        }
      }
      asm volatile("s_waitcnt vmcnt(4)" ::: "memory");  // stage(p+1) drained
      __builtin_amdgcn_s_barrier();
    }
    // rbuf[(4h+3)%3] == rbuf[h%3] dead until stage(4h+6)
    char* dead = (char*)&rbuf[h % 3][0];   // kT swz [64 d][64 r]; vT at +8192 B

    float sk = 0.f, sk2 = 0.f, sv = 0.f, sv2 = 0.f;
#pragma unroll
    for (int cc = 0; cc < 8; ++cc)
#pragma unroll
      for (int j = 0; j < 4; ++j) {
        float u = acc[cc][j];
        if (cc < 4) { sk += u; sk2 += u * u; } else { sv += u; sv2 += u * u; }
      }
    sk += __shfl_xor(sk, 16, 64);  sk += __shfl_xor(sk, 32, 64);
    sk2 += __shfl_xor(sk2, 16, 64); sk2 += __shfl_xor(sk2, 32, 64);
    sv += __shfl_xor(sv, 16, 64);  sv += __shfl_xor(sv, 32, 64);
    sv2 += __shfl_xor(sv2, 16, 64); sv2 += __shfl_xor(sv2, 32, 64);
    float mk = sk * 0.015625f, mv = sv * 0.015625f;
    float ik = rsqrtf(sk2 * 0.015625f - mk * mk + 1e-5f);
    float iv = rsqrtf(sv2 * 0.015625f - mv * mv + 1e-5f);

    half4 ok[4], ov[4];
#pragma unroll
    for (int j = 0; j < 4; ++j) {
      float k0 = (acc[0][j] - mk) * ik, k1 = (acc[1][j] - mk) * ik;
      float k2 = (acc[2][j] - mk) * ik, k3 = (acc[3][j] - mk) * ik;
      ok[0][j] = (_Float16)(k0 * cxj[j] - k1 * sxj[j]);
      ok[1][j] = (_Float16)(k1 * cxj[j] + k0 * sxj[j]);
      ok[2][j] = (_Float16)(k2 * cyj[j] - k3 * syj[j]);
      ok[3][j] = (_Float16)(k3 * cyj[j] + k2 * syj[j]);
      ov[0][j] = (_Float16)((acc[4][j] - mv) * iv);
      ov[1][j] = (_Float16)((acc[5][j] - mv) * iv);
      ov[2][j] = (_Float16)((acc[6][j] - mv) * iv);
      ov[3][j] = (_Float16)((acc[7][j] - mv) * iv);
    }
    // k,v -> dead slot, XOR-swizzled transpose: byte = d*128 + ((r*2)^((d&7)<<4))
    {
      const int r2 = (wv * 16 + lr) * 2;
#pragma unroll
      for (int cc = 0; cc < 4; ++cc)
#pragma unroll
        for (int j = 0; j < 4; ++j) {
          int d = cc * 16 + lg * 4 + j;
          int off = d * 128 + (r2 ^ ((d & 7) << 4));
          *(_Float16*)(dead + off) = ok[cc][j];
          *(_Float16*)(dead + 8192 + off) = ov[cc][j];
        }
    }
    asm volatile("s_waitcnt lgkmcnt(0)" ::: "memory");
    __builtin_amdgcn_s_barrier();

    // ---- dots partial: D[d][e] = sum_rows kT[d][r] vT[e][r], K=64 ----
    f32x4 dacc[4] = {};
#pragma unroll
    for (int ks = 0; ks < 2; ++ks) {
      int rb = (ks * 32 + lg * 8) * 2;             // row-byte, 16B aligned
      int da = wv * 16 + lr;
      half8 adf = *(const half8*)(dead + da * 128 + (rb ^ ((da & 7) << 4)));
#pragma unroll
      for (int ep = 0; ep < 4; ++ep) {
        int ea = ep * 16 + lr;
        half8 bdf = *(const half8*)(dead + 8192 + ea * 128 + (rb ^ ((ea & 7) << 4)));
        dacc[ep] = __builtin_amdgcn_mfma_f32_16x16x32_f16(adf, bdf, dacc[ep], 0, 0, 0);
      }
    }
    asm volatile("s_waitcnt lgkmcnt(0)" ::: "memory");   // dots reads done
    __builtin_amdgcn_s_barrier();                        // before restage of dead slot

    // partial layout [e][d]: lane holds d = wv*16 + lg*4+{0..3}, e = ep*16+lr
    _Float16* pdst = part16 + ((size_t)rowtile * 8 + habs) * 4096;
#pragma unroll
    for (int ep = 0; ep < 4; ++ep) {
      half4 o;
#pragma unroll
      for (int j = 0; j < 4; ++j) o[j] = (_Float16)dacc[ep][j];
      *(half4*)(pdst + (ep * 16 + lr) * 64 + wv * 16 + lg * 4) = o;
    }
  }
}

// ---------------- K2: reduce 512 rowtile partials -> dots fp32 [32 bh][e*64+d] ----
__global__ void __launch_bounds__(256) k_pred(const _Float16* __restrict__ part16,
                                              float* __restrict__ dots) {
  __shared__ float red[4][512];
  const int bh = blockIdx.x >> 3, sl = blockIdx.x & 7;
  const int b = bh >> 3, h = bh & 7;
  const int t = threadIdx.x, wv = t >> 6, l = t & 63;
  float s[8] = {};
  const _Float16* base = part16 + ((size_t)(b * 128) * 8 + h) * 4096 + sl * 512 + l * 8;
#pragma unroll 4
  for (int i = 0; i < 32; ++i) {
    int rt = wv * 32 + i;
    half8 v = *(const half8*)(base + (size_t)rt * 32768);
#pragma unroll
    for (int m = 0; m < 8; ++m) s[m] += (float)v[m];
  }
#pragma unroll
  for (int m = 0; m < 8; ++m) red[wv][l * 8 + m] = s[m];
  __syncthreads();
#pragma unroll
  for (int e = t; e < 512; e += 256) {
    float r = red[0][e] + red[1][e] + red[2][e] + red[3][e];
    dots[(size_t)bh * 4096 + sl * 512 + e] = r;
  }
}

// ---------------- K2b: wdt[b][j][h*64+d] = (1/N) sum_e dotsT[e][d] wout[h*64+e][j]
__global__ void __launch_bounds__(256) k_wd(const float* __restrict__ dots,
                                            const float* __restrict__ wout,
                                            _Float16* __restrict__ wdt) {
  __shared__ alignas(16) _Float16 a_lds[4096];
  __shared__ alignas(16) _Float16 b_lds[4096];
  const int bid = blockIdx.x, b = bid >> 3, hh = bid & 7;
  const int j0 = blockIdx.y * 64;
  const int t = threadIdx.x, wv = t >> 6, l = t & 63, lr = l & 15, lg = l >> 4;

#pragma unroll
  for (int g = 0; g < 4; ++g) {
    int i4 = (g * 256 + t) * 4;
    f32x4 s = *(const f32x4*)(dots + (size_t)bid * 4096 + i4);
    int e = i4 >> 6, d0 = i4 & 63;
#pragma unroll
    for (int m = 0; m < 4; ++m) {
      int d = d0 + m;
      *(_Float16*)((char*)a_lds + d * 128 + ((e * 2) ^ ((d & 7) << 4))) =
          (_Float16)(s[m] * (1.0f / 8192.0f));
    }
  }
#pragma unroll
  for (int g = 0; g < 4; ++g) {
    int i4 = (g * 256 + t) * 4;
    int e = i4 >> 6, jl0 = i4 & 63;
    f32x4 u = *(const f32x4*)(wout + (size_t)(hh * 64 + e) * 256 + j0 + jl0);
#pragma unroll
    for (int m = 0; m < 4; ++m) {
      int jl = jl0 + m;
      *(_Float16*)((char*)b_lds + jl * 128 + ((e * 2) ^ ((jl & 7) << 4))) = (_Float16)u[m];
    }
  }
  __syncthreads();

  f32x4 acc[4] = {};
#pragma unroll
  for (int sp = 0; sp < 2; ++sp) {
    int kb = sp * 64 + lg * 16;
    half8 bf;
    {
      int jl = wv * 16 + lr;
      bf = *(const half8*)((const char*)b_lds + jl * 128 + (kb ^ ((jl & 7) << 4)));
    }
#pragma unroll
    for (int ad = 0; ad < 4; ++ad) {
      int d = ad * 16 + lr;
      half8 af = *(const half8*)((const char*)a_lds + d * 128 + (kb ^ ((d & 7) << 4)));
      acc[ad] = __builtin_amdgcn_mfma_f32_16x16x32_f16(af, bf, acc[ad], 0, 0, 0);
    }
  }
#pragma unroll
  for (int ad = 0; ad < 4; ++ad) {
    int j = j0 + wv * 16 + lr;
    half4 o;
#pragma unroll
    for (int jj = 0; jj < 4; ++jj) o[jj] = (_Float16)acc[ad][jj];
    *(half4*)(wdt + (size_t)b * 131072 + (size_t)j * 512 + hh * 64 + ad * 16 + lg * 4) = o;
  }
}

// ---------------- K3: out = rope(x@Wq) @ wdt[b] + b_out  [R15-v1 exact] ----------------
__global__ void __launch_bounds__(256) k_out(const float* __restrict__ x,
                                             const _Float16* __restrict__ wt,
                                             const float* __restrict__ pos,
                                             const _Float16* __restrict__ wdt,
                                             const float* __restrict__ bout,
                                             float* __restrict__ out) {
  __shared__ alignas(16) _Float16 wqr[3][4096];    // [64 qcols][64 K] swizzled, 8 KB x3
  __shared__ alignas(16) _Float16 qtile[4096];     // [64 rows][64 d] swizzled, 8 KB
  __shared__ alignas(16) _Float16 wtile[16384];    // [256 j][64 d] swizzled, 32 KB
  const int row0 = blockIdx.x * 64;
  const int b = row0 >> 13;
  const int t = threadIdx.x, wv = t >> 6, l = t & 63, lr = l & 15, lg = l >> 4;
  const int rh = wv >> 1, cq = wv & 1;
  const int myrow = row0 + wv * 16 + lr;

  half8 afr[8];
#pragma unroll
  for (int c = 0; c < 8; ++c) {
    const float* src = x + (size_t)myrow * 256 + c * 32 + lg * 8;
    float4 a = *(const float4*)src;
    float4 bb = *(const float4*)(src + 4);
    half8 hv;
    hv[0] = (_Float16)a.x; hv[1] = (_Float16)a.y; hv[2] = (_Float16)a.z; hv[3] = (_Float16)a.w;
    hv[4] = (_Float16)bb.x; hv[5] = (_Float16)bb.y; hv[6] = (_Float16)bb.z; hv[7] = (_Float16)bb.w;
    afr[c] = hv;
  }

  const float px = pos[(size_t)myrow * 2 + 0] * 64.0f;
  const float py = pos[(size_t)myrow * 2 + 1] * 64.0f;
  float sxj[4], cxj[4], syj[4], cyj[4];
#pragma unroll
  for (int j = 0; j < 4; ++j) {
    float invf = exp2f((float)(lg * 4 + j) * -0.8304820237218405f);
    __sincosf(px * invf, &sxj[j], &cxj[j]);
    __sincosf(py * invf, &syj[j], &cyj[j]);
  }

  auto stageWT = [&](int hh) {
#pragma unroll
    for (int call = 0; call < 8; ++call) {
      int ob = (call * 4 + wv) * 1024;
      int o = ob + l * 16;
      int c = o >> 7;                              // j 0..255
      int kb = (o & 127) ^ ((c & 7) << 4);
      const char* src = (const char*)(wdt + (size_t)b * 131072 + (size_t)c * 512 + hh * 64) + kb;
      GLL(src, (char*)wtile + ob);
    }
  };
  auto stageWQ = [&](int p) {
    const int pd = p & 31;
    const int hq = pd >> 2, ktq = pd & 3;
    char* dst = (char*)&wqr[p % 3][0];
#pragma unroll
    for (int call = 0; call < 2; ++call) {
      int ob = (call * 4 + wv) * 1024;
      int o = ob + l * 16;
      int c = o >> 7;                              // q col 0..63
      int kb = (o & 127) ^ ((c & 7) << 4);
      int gc = (hq << 6) + (c & 63);
      const char* src = (const char*)(wt + (size_t)gc * 256 + ktq * 64) + kb;
      GLL(src, dst + ob);
    }
  };

  stageWT(0); stageWQ(0); stageWQ(1);
  asm volatile("s_waitcnt vmcnt(2)" ::: "memory");
  __builtin_amdgcn_s_barrier();

  f32x4 aco[8][2] = {};
#pragma unroll 1
  for (int h = 0; h < 8; ++h) {
    f32x4 aq[4] = {};
#pragma unroll
    for (int sub = 0; sub < 4; ++sub) {
      const int p = h * 4 + sub;
      stageWQ(p + 2);
      const char* wbp = (const char*)&wqr[p % 3][0];
#pragma unroll
      for (int sp = 0; sp < 2; ++sp) {
        half8 af = afr[sub * 2 + sp];
        int wkb = sp * 64 + lg * 16;
#pragma unroll
        for (int cf = 0; cf < 4; ++cf) {
          int c = cf * 16 + lr;
          half8 bf = *(const half8*)(wbp + c * 128 + (wkb ^ ((c & 7) << 4)));
          aq[cf] = __builtin_amdgcn_mfma_f32_16x16x32_f16(bf, af, aq[cf], 0, 0, 0);
        }
      }
      asm volatile("s_waitcnt vmcnt(2)" ::: "memory");
      __builtin_amdgcn_s_barrier();
    }
    {
      half4 oq[4];
#pragma unroll
      for (int j = 0; j < 4; ++j) {
        float q0 = aq[0][j], q1 = aq[1][j], q2 = aq[2][j], q3 = aq[3][j];
        oq[0][j] = (_Float16)(q0 * cxj[j] - q1 * sxj[j]);
        oq[1][j] = (_Float16)(q1 * cxj[j] + q0 * sxj[j]);
        oq[2][j] = (_Float16)(q2 * cyj[j] - q3 * syj[j]);
        oq[3][j] = (_Float16)(q3 * cyj[j] + q2 * syj[j]);
      }
      int row = wv * 16 + lr;
#pragma unroll
      for (int cc = 0; cc < 4; ++cc)
        *(half4*)((char*)qtile + row * 128 + ((cc * 32 + lg * 8) ^ ((row & 7) << 4))) = oq[cc];
    }
    asm volatile("s_waitcnt lgkmcnt(0)" ::: "memory");
    __builtin_amdgcn_s_barrier();

#pragma unroll
    for (int sp = 0; sp < 2; ++sp) {
      int kb = sp * 64 + lg * 16;
      half8 af2[2];
#pragma unroll
      for (int rs = 0; rs < 2; ++rs) {
        int arow = rh * 32 + rs * 16 + lr;
        af2[rs] = *(const half8*)((const char*)qtile + arow * 128 + (kb ^ ((arow & 7) << 4)));
      }
#pragma unroll
      for (int cf = 0; cf < 8; ++cf) {
        int c = cq * 128 + cf * 16 + lr;
        half8 bf = *(const half8*)((const char*)wtile + c * 128 + (kb ^ ((c & 7) << 4)));
#pragma unroll
        for (int rs = 0; rs < 2; ++rs)
          aco[cf][rs] = __builtin_amdgcn_mfma_f32_16x16x32_f16(af2[rs], bf, aco[cf][rs], 0, 0, 0);
      }
    }
    asm volatile("s_waitcnt lgkmcnt(0)" ::: "memory");
    __builtin_amdgcn_s_barrier();
    if (h < 7) stageWT(h + 1);
  }
#pragma unroll
  for (int cf = 0; cf < 8; ++cf) {
    int col = cq * 128 + cf * 16 + lr;
    float bo = bout[col];
#pragma unroll
    for (int rs = 0; rs < 2; ++rs)
#pragma unroll
      for (int j = 0; j < 4; ++j) {
        int grow = row0 + rh * 32 + rs * 16 + lg * 4 + j;
        out[(size_t)grow * 256 + col] = aco[cf][rs][j] + bo;
      }
  }
}

// ---------------- launch ----------------
extern "C" void kernel_launch(void* const* d_in, const int* in_sizes, int n_in,
                              void* d_out, int out_size, void* d_ws, size_t ws_size,
                              hipStream_t stream) {
  const float* x    = (const float*)d_in[0];
  const float* pos  = (const float*)d_in[1];
  const float* wqkv = (const float*)d_in[2];
  const float* wout = (const float*)d_in[3];
  const float* bout = (const float*)d_in[4];
  float* out = (float*)d_out;
  char* ws = (char*)d_ws;

  _Float16* wt16   = (_Float16*)(ws + 0);          //    786,432 B
  _Float16* part16 = (_Float16*)(ws + 786432);     // 33,554,432 B
  float*    dots   = (float*)   (ws + 34340864);   //    524,288 B
  _Float16* wdt    = (_Float16*)(ws + 34865152);   //  1,048,576 B (end 35,913,728)

  k_cvt_w<<<1536, 256, 0, stream>>>(wqkv, wt16);
  k_qkv<<<1024, 256, 0, stream>>>(x, wt16, pos, part16);
  k_pred<<<256, 256, 0, stream>>>(part16, dots);
  k_wd<<<dim3(32, 4), 256, 0, stream>>>(dots, wout, wdt);
  k_out<<<512, 256, 0, stream>>>(x, wt16, pos, wdt, bout, out);
}

// Round 20
// 97.041 us; speedup vs baseline: 1.0661x; 1.0530x over previous
//
#include <hip/hip_runtime.h>
#include <hip/hip_fp16.h>

#define BB 4
#define NN 8192
#define DD 256
#define HH 8
#define MM 32768   // BB*NN

typedef __attribute__((ext_vector_type(8))) _Float16 half8;
typedef __attribute__((ext_vector_type(4))) _Float16 half4;
typedef __attribute__((ext_vector_type(4))) float f32x4;

#define GLL(src, dst)                                                        \
  __builtin_amdgcn_global_load_lds(                                          \
      (const __attribute__((address_space(1))) void*)(src),                  \
      (__attribute__((address_space(3))) void*)(dst), 16, 0, 0)

// ---------------- K0: W conversion ----------------
// W_qkv [256][1536] fp32 -> Wt [1536][256] fp16 (transposed)
__global__ void __launch_bounds__(256) k_cvt_w(const float* __restrict__ w,
                                               _Float16* __restrict__ wt) {
  int idx = blockIdx.x * 256 + threadIdx.x;  // 0..393215
  int k = idx / 1536, c = idx % 1536;
  wt[(size_t)c * 256 + k] = (_Float16)w[idx];
}

// ---------------- K1: kv GEMM + norm + rotary + fused dots-partial ----------------
// [R15 structure + R19's zero-conflict swizzled kv scratch]
// 64 rows, 8 heads, cols = k(64)+v(64). 3-buffer W ring (24 KB slots, 4 GLL/
// stage), counted vmcnt(4): stage(p+1) drained at end of phase p. kv scratch =
// XOR-swizzled [64 d][64 r] (kT 8KB + vT 8KB) inside the dead ring slot.
__global__ void __launch_bounds__(256) k_qkv(const float* __restrict__ x,
                                             const _Float16* __restrict__ wt,
                                             const float* __restrict__ pos,
                                             _Float16* __restrict__ part16) {
  __shared__ alignas(16) _Float16 rbuf[3][12288];  // 24 KB x3
  const int row0 = blockIdx.x * 64;
  const int t = threadIdx.x;
  const int wv = t >> 6, l = t & 63, lr = l & 15, lg = l >> 4;
  const int myrow = row0 + wv * 16 + lr;

  half8 afr[8];
#pragma unroll
  for (int c = 0; c < 8; ++c) {      // c = kt*2 + sp
    const float* src = x + (size_t)myrow * 256 + c * 32 + lg * 8;
    float4 a = *(const float4*)src;
    float4 b = *(const float4*)(src + 4);
    half8 hv;
    hv[0] = (_Float16)a.x; hv[1] = (_Float16)a.y; hv[2] = (_Float16)a.z; hv[3] = (_Float16)a.w;
    hv[4] = (_Float16)b.x; hv[5] = (_Float16)b.y; hv[6] = (_Float16)b.z; hv[7] = (_Float16)b.w;
    afr[c] = hv;
  }

  const float px = pos[(size_t)myrow * 2 + 0] * 64.0f;
  const float py = pos[(size_t)myrow * 2 + 1] * 64.0f;
  float sxj[4], cxj[4], syj[4], cyj[4];
#pragma unroll
  for (int j = 0; j < 4; ++j) {
    float invf = exp2f((float)(lg * 4 + j) * -0.8304820237218405f);  // 10000^(-fi/16)
    __sincosf(px * invf, &sxj[j], &cxj[j]);
    __sincosf(py * invf, &syj[j], &cyj[j]);
  }

  // ---- W stage for phase p (p = h*4 + kt, wraps mod 32): k,v sections ----
  auto stageP = [&](int p) {
    const int pd = p & 31;
    const int hh = pd >> 2, kt = pd & 3;
    char* dst = (char*)&rbuf[p % 3][0];
#pragma unroll
    for (int call = 0; call < 4; ++call) {
      int ob = (call * 4 + wv) * 1024;
      int o = ob + l * 16;
      int c = o >> 7;                              // col 0..127 (0-63=k, 64-127=v)
      int kb = (o & 127) ^ ((c & 7) << 4);
      int gc = ((c >> 6) + 1) * 512 + (hh << 6) + (c & 63);
      const char* src = (const char*)(wt + (size_t)gc * 256 + kt * 64) + kb;
      GLL(src, dst + ob);
    }
  };

  stageP(0); stageP(1);
  asm volatile("s_waitcnt vmcnt(4)" ::: "memory");   // stage(0) complete
  __builtin_amdgcn_s_barrier();

#pragma unroll 1
  for (int h = 0; h < 8; ++h) {
    f32x4 acc[8] = {};                 // 0-3 = k, 4-7 = v
#pragma unroll
    for (int kt = 0; kt < 4; ++kt) {
      const int p = h * 4 + kt;
      stageP(p + 2);                   // UNCONDITIONAL: uniform op-count
      const char* wbp = (const char*)&rbuf[p % 3][0];
#pragma unroll
      for (int sp = 0; sp < 2; ++sp) {
        half8 af = afr[kt * 2 + sp];
        int wkb = sp * 64 + lg * 16;
#pragma unroll
        for (int cf = 0; cf < 8; ++cf) {
          int c = cf * 16 + lr;
          half8 bf = *(const half8*)(wbp + c * 128 + (wkb ^ ((c & 7) << 4)));
          // SWAPPED: A = W fragment, B = x fragment -> D[wcol][xrow]
          acc[cf] = __builtin_amdgcn_mfma_f32_16x16x32_f16(bf, af, acc[cf], 0, 0, 0);
        }
      }
      asm volatile("s_waitcnt vmcnt(4)" ::: "memory");  // stage(p+1) drained
      __builtin_amdgcn_s_barrier();
    }
    // rbuf[(4h+3)%3] == rbuf[h%3] dead until stage(4h+6)
    char* dead = (char*)&rbuf[h % 3][0];   // kT swz [64 d][64 r]; vT at +8192 B

    float sk = 0.f, sk2 = 0.f, sv = 0.f, sv2 = 0.f;
#pragma unroll
    for (int cc = 0; cc < 8; ++cc)
#pragma unroll
      for (int j = 0; j < 4; ++j) {
        float u = acc[cc][j];
        if (cc < 4) { sk += u; sk2 += u * u; } else { sv += u; sv2 += u * u; }
      }
    sk += __shfl_xor(sk, 16, 64);  sk += __shfl_xor(sk, 32, 64);
    sk2 += __shfl_xor(sk2, 16, 64); sk2 += __shfl_xor(sk2, 32, 64);
    sv += __shfl_xor(sv, 16, 64);  sv += __shfl_xor(sv, 32, 64);
    sv2 += __shfl_xor(sv2, 16, 64); sv2 += __shfl_xor(sv2, 32, 64);
    float mk = sk * 0.015625f, mv = sv * 0.015625f;
    float ik = rsqrtf(sk2 * 0.015625f - mk * mk + 1e-5f);
    float iv = rsqrtf(sv2 * 0.015625f - mv * mv + 1e-5f);

    half4 ok[4], ov[4];
#pragma unroll
    for (int j = 0; j < 4; ++j) {
      float k0 = (acc[0][j] - mk) * ik, k1 = (acc[1][j] - mk) * ik;
      float k2 = (acc[2][j] - mk) * ik, k3 = (acc[3][j] - mk) * ik;
      ok[0][j] = (_Float16)(k0 * cxj[j] - k1 * sxj[j]);
      ok[1][j] = (_Float16)(k1 * cxj[j] + k0 * sxj[j]);
      ok[2][j] = (_Float16)(k2 * cyj[j] - k3 * syj[j]);
      ok[3][j] = (_Float16)(k3 * cyj[j] + k2 * syj[j]);
      ov[0][j] = (_Float16)((acc[4][j] - mv) * iv);
      ov[1][j] = (_Float16)((acc[5][j] - mv) * iv);
      ov[2][j] = (_Float16)((acc[6][j] - mv) * iv);
      ov[3][j] = (_Float16)((acc[7][j] - mv) * iv);
    }
    // k,v -> dead slot, XOR-swizzled transpose: byte = d*128 + ((r*2)^((d&7)<<4))
    // (R19-verified, zero bank conflicts)
    {
      const int r2 = (wv * 16 + lr) * 2;
#pragma unroll
      for (int cc = 0; cc < 4; ++cc)
#pragma unroll
        for (int j = 0; j < 4; ++j) {
          int d = cc * 16 + lg * 4 + j;
          int off = d * 128 + (r2 ^ ((d & 7) << 4));
          *(_Float16*)(dead + off) = ok[cc][j];
          *(_Float16*)(dead + 8192 + off) = ov[cc][j];
        }
    }
    asm volatile("s_waitcnt lgkmcnt(0)" ::: "memory");
    __builtin_amdgcn_s_barrier();

    // ---- dots partial: D[d][e] = sum_rows kT[d][r] vT[e][r], K=64 ----
    f32x4 dacc[4] = {};
#pragma unroll
    for (int ks = 0; ks < 2; ++ks) {
      int rb = (ks * 32 + lg * 8) * 2;             // row-byte, 16B aligned
      int da = wv * 16 + lr;
      half8 adf = *(const half8*)(dead + da * 128 + (rb ^ ((da & 7) << 4)));
#pragma unroll
      for (int ep = 0; ep < 4; ++ep) {
        int ea = ep * 16 + lr;
        half8 bdf = *(const half8*)(dead + 8192 + ea * 128 + (rb ^ ((ea & 7) << 4)));
        dacc[ep] = __builtin_amdgcn_mfma_f32_16x16x32_f16(adf, bdf, dacc[ep], 0, 0, 0);
      }
    }
    asm volatile("s_waitcnt lgkmcnt(0)" ::: "memory");   // dots reads done
    __builtin_amdgcn_s_barrier();                        // before restage of dead slot

    // partial layout [e][d]: lane holds d = wv*16 + lg*4+{0..3}, e = ep*16+lr
    _Float16* pdst = part16 + ((size_t)blockIdx.x * 8 + h) * 4096;
#pragma unroll
    for (int ep = 0; ep < 4; ++ep) {
      half4 o;
#pragma unroll
      for (int j = 0; j < 4; ++j) o[j] = (_Float16)dacc[ep][j];
      *(half4*)(pdst + (ep * 16 + lr) * 64 + wv * 16 + lg * 4) = o;
    }
  }
}

// ---------------- K2: reduce 512 rowtile partials -> dots fp32 [32 bh][e*64+d] ----
__global__ void __launch_bounds__(256) k_pred(const _Float16* __restrict__ part16,
                                              float* __restrict__ dots) {
  __shared__ float red[4][512];
  const int bh = blockIdx.x >> 3, sl = blockIdx.x & 7;
  const int b = bh >> 3, h = bh & 7;
  const int t = threadIdx.x, wv = t >> 6, l = t & 63;
  float s[8] = {};
  const _Float16* base = part16 + ((size_t)(b * 128) * 8 + h) * 4096 + sl * 512 + l * 8;
#pragma unroll 4
  for (int i = 0; i < 32; ++i) {
    int rt = wv * 32 + i;
    half8 v = *(const half8*)(base + (size_t)rt * 32768);
#pragma unroll
    for (int m = 0; m < 8; ++m) s[m] += (float)v[m];
  }
#pragma unroll
  for (int m = 0; m < 8; ++m) red[wv][l * 8 + m] = s[m];
  __syncthreads();
#pragma unroll
  for (int e = t; e < 512; e += 256) {
    float r = red[0][e] + red[1][e] + red[2][e] + red[3][e];
    dots[(size_t)bh * 4096 + sl * 512 + e] = r;
  }
}

// ---------------- K2b: wdt[b][j][h*64+d] = (1/N) sum_e dotsT[e][d] wout[h*64+e][j]
__global__ void __launch_bounds__(256) k_wd(const float* __restrict__ dots,
                                            const float* __restrict__ wout,
                                            _Float16* __restrict__ wdt) {
  __shared__ alignas(16) _Float16 a_lds[4096];
  __shared__ alignas(16) _Float16 b_lds[4096];
  const int bid = blockIdx.x, b = bid >> 3, hh = bid & 7;
  const int j0 = blockIdx.y * 64;
  const int t = threadIdx.x, wv = t >> 6, l = t & 63, lr = l & 15, lg = l >> 4;

#pragma unroll
  for (int g = 0; g < 4; ++g) {
    int i4 = (g * 256 + t) * 4;
    f32x4 s = *(const f32x4*)(dots + (size_t)bid * 4096 + i4);
    int e = i4 >> 6, d0 = i4 & 63;
#pragma unroll
    for (int m = 0; m < 4; ++m) {
      int d = d0 + m;
      *(_Float16*)((char*)a_lds + d * 128 + ((e * 2) ^ ((d & 7) << 4))) =
          (_Float16)(s[m] * (1.0f / 8192.0f));
    }
  }
#pragma unroll
  for (int g = 0; g < 4; ++g) {
    int i4 = (g * 256 + t) * 4;
    int e = i4 >> 6, jl0 = i4 & 63;
    f32x4 u = *(const f32x4*)(wout + (size_t)(hh * 64 + e) * 256 + j0 + jl0);
#pragma unroll
    for (int m = 0; m < 4; ++m) {
      int jl = jl0 + m;
      *(_Float16*)((char*)b_lds + jl * 128 + ((e * 2) ^ ((jl & 7) << 4))) = (_Float16)u[m];
    }
  }
  __syncthreads();

  f32x4 acc[4] = {};
#pragma unroll
  for (int sp = 0; sp < 2; ++sp) {
    int kb = sp * 64 + lg * 16;
    half8 bf;
    {
      int jl = wv * 16 + lr;
      bf = *(const half8*)((const char*)b_lds + jl * 128 + (kb ^ ((jl & 7) << 4)));
    }
#pragma unroll
    for (int ad = 0; ad < 4; ++ad) {
      int d = ad * 16 + lr;
      half8 af = *(const half8*)((const char*)a_lds + d * 128 + (kb ^ ((d & 7) << 4)));
      acc[ad] = __builtin_amdgcn_mfma_f32_16x16x32_f16(af, bf, acc[ad], 0, 0, 0);
    }
  }
#pragma unroll
  for (int ad = 0; ad < 4; ++ad) {
    int j = j0 + wv * 16 + lr;
    half4 o;
#pragma unroll
    for (int jj = 0; jj < 4; ++jj) o[jj] = (_Float16)acc[ad][jj];
    *(half4*)(wdt + (size_t)b * 131072 + (size_t)j * 512 + hh * 64 + ad * 16 + lg * 4) = o;
  }
}

// ---------------- K3: out = rope(x@Wq) @ wdt[b] + b_out  [R15-v1 exact] ----------------
__global__ void __launch_bounds__(256) k_out(const float* __restrict__ x,
                                             const _Float16* __restrict__ wt,
                                             const float* __restrict__ pos,
                                             const _Float16* __restrict__ wdt,
                                             const float* __restrict__ bout,
                                             float* __restrict__ out) {
  __shared__ alignas(16) _Float16 wqr[3][4096];    // [64 qcols][64 K] swizzled, 8 KB x3
  __shared__ alignas(16) _Float16 qtile[4096];     // [64 rows][64 d] swizzled, 8 KB
  __shared__ alignas(16) _Float16 wtile[16384];    // [256 j][64 d] swizzled, 32 KB
  const int row0 = blockIdx.x * 64;
  const int b = row0 >> 13;
  const int t = threadIdx.x, wv = t >> 6, l = t & 63, lr = l & 15, lg = l >> 4;
  const int rh = wv >> 1, cq = wv & 1;
  const int myrow = row0 + wv * 16 + lr;

  half8 afr[8];
#pragma unroll
  for (int c = 0; c < 8; ++c) {
    const float* src = x + (size_t)myrow * 256 + c * 32 + lg * 8;
    float4 a = *(const float4*)src;
    float4 bb = *(const float4*)(src + 4);
    half8 hv;
    hv[0] = (_Float16)a.x; hv[1] = (_Float16)a.y; hv[2] = (_Float16)a.z; hv[3] = (_Float16)a.w;
    hv[4] = (_Float16)bb.x; hv[5] = (_Float16)bb.y; hv[6] = (_Float16)bb.z; hv[7] = (_Float16)bb.w;
    afr[c] = hv;
  }

  const float px = pos[(size_t)myrow * 2 + 0] * 64.0f;
  const float py = pos[(size_t)myrow * 2 + 1] * 64.0f;
  float sxj[4], cxj[4], syj[4], cyj[4];
#pragma unroll
  for (int j = 0; j < 4; ++j) {
    float invf = exp2f((float)(lg * 4 + j) * -0.8304820237218405f);
    __sincosf(px * invf, &sxj[j], &cxj[j]);
    __sincosf(py * invf, &syj[j], &cyj[j]);
  }

  auto stageWT = [&](int hh) {
#pragma unroll
    for (int call = 0; call < 8; ++call) {
      int ob = (call * 4 + wv) * 1024;
      int o = ob + l * 16;
      int c = o >> 7;                              // j 0..255
      int kb = (o & 127) ^ ((c & 7) << 4);
      const char* src = (const char*)(wdt + (size_t)b * 131072 + (size_t)c * 512 + hh * 64) + kb;
      GLL(src, (char*)wtile + ob);
    }
  };
  auto stageWQ = [&](int p) {
    const int pd = p & 31;
    const int hq = pd >> 2, ktq = pd & 3;
    char* dst = (char*)&wqr[p % 3][0];
#pragma unroll
    for (int call = 0; call < 2; ++call) {
      int ob = (call * 4 + wv) * 1024;
      int o = ob + l * 16;
      int c = o >> 7;                              // q col 0..63
      int kb = (o & 127) ^ ((c & 7) << 4);
      int gc = (hq << 6) + (c & 63);
      const char* src = (const char*)(wt + (size_t)gc * 256 + ktq * 64) + kb;
      GLL(src, dst + ob);
    }
  };

  stageWT(0); stageWQ(0); stageWQ(1);
  asm volatile("s_waitcnt vmcnt(2)" ::: "memory");
  __builtin_amdgcn_s_barrier();

  f32x4 aco[8][2] = {};
#pragma unroll 1
  for (int h = 0; h < 8; ++h) {
    f32x4 aq[4] = {};
#pragma unroll
    for (int sub = 0; sub < 4; ++sub) {
      const int p = h * 4 + sub;
      stageWQ(p + 2);
      const char* wbp = (const char*)&wqr[p % 3][0];
#pragma unroll
      for (int sp = 0; sp < 2; ++sp) {
        half8 af = afr[sub * 2 + sp];
        int wkb = sp * 64 + lg * 16;
#pragma unroll
        for (int cf = 0; cf < 4; ++cf) {
          int c = cf * 16 + lr;
          half8 bf = *(const half8*)(wbp + c * 128 + (wkb ^ ((c & 7) << 4)));
          aq[cf] = __builtin_amdgcn_mfma_f32_16x16x32_f16(bf, af, aq[cf], 0, 0, 0);
        }
      }
      asm volatile("s_waitcnt vmcnt(2)" ::: "memory");
      __builtin_amdgcn_s_barrier();
    }
    {
      half4 oq[4];
#pragma unroll
      for (int j = 0; j < 4; ++j) {
        float q0 = aq[0][j], q1 = aq[1][j], q2 = aq[2][j], q3 = aq[3][j];
        oq[0][j] = (_Float16)(q0 * cxj[j] - q1 * sxj[j]);
        oq[1][j] = (_Float16)(q1 * cxj[j] + q0 * sxj[j]);
        oq[2][j] = (_Float16)(q2 * cyj[j] - q3 * syj[j]);
        oq[3][j] = (_Float16)(q3 * cyj[j] + q2 * syj[j]);
      }
      int row = wv * 16 + lr;
#pragma unroll
      for (int cc = 0; cc < 4; ++cc)
        *(half4*)((char*)qtile + row * 128 + ((cc * 32 + lg * 8) ^ ((row & 7) << 4))) = oq[cc];
    }
    asm volatile("s_waitcnt lgkmcnt(0)" ::: "memory");
    __builtin_amdgcn_s_barrier();

#pragma unroll
    for (int sp = 0; sp < 2; ++sp) {
      int kb = sp * 64 + lg * 16;
      half8 af2[2];
#pragma unroll
      for (int rs = 0; rs < 2; ++rs) {
        int arow = rh * 32 + rs * 16 + lr;
        af2[rs] = *(const half8*)((const char*)qtile + arow * 128 + (kb ^ ((arow & 7) << 4)));
      }
#pragma unroll
      for (int cf = 0; cf < 8; ++cf) {
        int c = cq * 128 + cf * 16 + lr;
        half8 bf = *(const half8*)((const char*)wtile + c * 128 + (kb ^ ((c & 7) << 4)));
#pragma unroll
        for (int rs = 0; rs < 2; ++rs)
          aco[cf][rs] = __builtin_amdgcn_mfma_f32_16x16x32_f16(af2[rs], bf, aco[cf][rs], 0, 0, 0);
      }
    }
    asm volatile("s_waitcnt lgkmcnt(0)" ::: "memory");
    __builtin_amdgcn_s_barrier();
    if (h < 7) stageWT(h + 1);
  }
#pragma unroll
  for (int cf = 0; cf < 8; ++cf) {
    int col = cq * 128 + cf * 16 + lr;
    float bo = bout[col];
#pragma unroll
    for (int rs = 0; rs < 2; ++rs)
#pragma unroll
      for (int j = 0; j < 4; ++j) {
        int grow = row0 + rh * 32 + rs * 16 + lg * 4 + j;
        out[(size_t)grow * 256 + col] = aco[cf][rs][j] + bo;
      }
  }
}

// ---------------- launch ----------------
extern "C" void kernel_launch(void* const* d_in, const int* in_sizes, int n_in,
                              void* d_out, int out_size, void* d_ws, size_t ws_size,
                              hipStream_t stream) {
  const float* x    = (const float*)d_in[0];
  const float* pos  = (const float*)d_in[1];
  const float* wqkv = (const float*)d_in[2];
  const float* wout = (const float*)d_in[3];
  const float* bout = (const float*)d_in[4];
  float* out = (float*)d_out;
  char* ws = (char*)d_ws;

  _Float16* wt16   = (_Float16*)(ws + 0);          //    786,432 B
  _Float16* part16 = (_Float16*)(ws + 786432);     // 33,554,432 B
  float*    dots   = (float*)   (ws + 34340864);   //    524,288 B
  _Float16* wdt    = (_Float16*)(ws + 34865152);   //  1,048,576 B (end 35,913,728)

  k_cvt_w<<<1536, 256, 0, stream>>>(wqkv, wt16);
  k_qkv<<<512, 256, 0, stream>>>(x, wt16, pos, part16);
  k_pred<<<256, 256, 0, stream>>>(part16, dots);
  k_wd<<<dim3(32, 4), 256, 0, stream>>>(dots, wout, wdt);
  k_out<<<512, 256, 0, stream>>>(x, wt16, pos, wdt, bout, out);
}